// Round 11
// baseline (321.566 us; speedup 1.0000x reference)
//
#include <hip/hip_runtime.h>
#include <hip/hip_cooperative_groups.h>
#include <math.h>

namespace cg = cooperative_groups;

#define BB 2
#define LL 4096
#define HH 8
#define DD 64
#define UU 45
#define TILE 128
#define NTILES (LL / TILE) // 32

// split-K attention config
#define NC 64              // key chunks
#define CK (LL / NC)       // 64 keys per chunk
#define KSTR 68            // padded LDS row stride (floats) for K/V/Q tiles
#define SSTR 68            // padded LDS row stride for scores (CK=64 + 4)

#define NB_CMU (BB * HH * LL / 4)  // 16384 computeM units (4 queries each)
#define NB_TS (BB * HH * NTILES)   // 512 tilesum units
#define NB_CU (BB * HH * NTILES)   // 512 cumsum units
#define NB_CO (BB * HH * UU / 4)   // 180 combine units (4 u's each)
#define GRIDB 768                  // coop grid: 3 blocks/CU (LDS 42.7KB x3 <=160KB)

__device__ __forceinline__ int qkv_idx(int b, int l, int h, int d) {
    return ((b * LL + l) * HH + h) * DD + d;
}

// DPP all-reduce helper: v += rotate-within-16-lane-row(v, N). VALU pipe only.
template <int CTRL>
__device__ __forceinline__ float dpp_add(float v) {
    int x = __builtin_amdgcn_update_dpp(0, __float_as_int(v), CTRL, 0xF, 0xF,
                                        true);
    return v + __int_as_float(x);
}

// ---------------- shared-memory overlays -------------------------------------
struct SmemTopk {
    unsigned keys[LL];       // 16 KB
    unsigned hist[256];
    unsigned scanbuf[256];
    unsigned sPrefix, sMask, sK, sBin;
    int outCount, eqCount;
    int eqIdx[64];
};
struct SmemAttn {
    float Qs[48 * KSTR];     // 13056 B
    float Ks[CK * KSTR];     // 17408 B (reused for V in PV phase)
    float Ss[UU * SSTR];     // 12240 B
};
struct SmemSum {
    float red[4][DD];
    float pre2[4][DD];
};

// ---------------- unit: sparsity metric M for one query (one wave) -----------
// 16 lanes per sampled K row (4 contiguous 256B runs per load -- segment-
// optimal). Rounds 7-10 established: kernel is TA/L1-throughput bound at
// ~50us; load batching (array/launch-bounds/sched_barrier/inline-asm) is
// mechanism-refuted. Clean form kept.
__device__ __forceinline__ void computeM_unit(
        int w, int lane, const float* __restrict__ Q,
        const float* __restrict__ K, const int* __restrict__ idx,
        float* __restrict__ M) {
    int q = w % LL;
    int bh = w / LL;            // b*HH + h
    int h = bh % HH, b = bh / HH;

    const float* Kbh = K + (size_t)(b * LL * HH + h) * DD;
    const size_t rowStride = (size_t)HH * DD; // 512 floats between key rows

    int r = lane >> 4;    // which of 4 rows this lane helps load (DPP row id)
    int c16 = lane & 15;  // position within 16-lane row group

    const float4 qf = *(const float4*)(Q + qkv_idx(b, q, h, c16 * 4));
    const int* idxRow = idx + q * UU;

    int ks[12];
#pragma unroll
    for (int g = 0; g < 12; ++g) {
        int s = g * 4 + r;
        ks[g] = idxRow[s < UU ? s : 0];  // clamped (row-end OOB guard)
    }
    float4 kk[12];
#pragma unroll
    for (int g = 0; g < 12; ++g)
        kk[g] = ((const float4*)(Kbh + (size_t)ks[g] * rowStride))[c16];

    float mval = -INFINITY, sval = 0.f;
#pragma unroll
    for (int g = 0; g < 12; ++g) {
        float part = fmaf(kk[g].x, qf.x,
                     fmaf(kk[g].y, qf.y,
                     fmaf(kk[g].z, qf.z, kk[g].w * qf.w)));
        part = dpp_add<0x128>(part); // row_ror:8
        part = dpp_add<0x124>(part); // row_ror:4
        part = dpp_add<0x122>(part); // row_ror:2
        part = dpp_add<0x121>(part); // row_ror:1
        int s = g * 4 + r;
        if (s < UU) { mval = fmaxf(mval, part); sval += part; }
    }
    mval = fmaxf(mval, __shfl_xor(mval, 16, 64));
    sval += __shfl_xor(sval, 16, 64);
    mval = fmaxf(mval, __shfl_xor(mval, 32, 64));
    sval += __shfl_xor(sval, 32, 64);
    if (lane == 0) M[bh * LL + q] = mval - sval * (1.0f / LL);
}

// ---------------- unit: V tile sum -------------------------------------------
__device__ __forceinline__ void tilesum_unit(
        int blk, int t, const float* __restrict__ V, float* __restrict__ tsum,
        float (*red)[DD]) {
    int tile = blk % NTILES;
    int bh = blk / NTILES;
    int h = bh % HH, b = bh / HH;
    int d = t & 63, g = t >> 6; // g in 0..3
    const int CH = TILE / 4;    // 32
    int l0 = tile * TILE + g * CH;
    float acc = 0.f;
    for (int i = 0; i < CH; ++i) acc += V[qkv_idx(b, l0 + i, h, d)];
    red[g][d] = acc;
    __syncthreads();
    if (g == 0)
        tsum[blk * DD + d] = red[0][d] + red[1][d] + red[2][d] + red[3][d];
}

// ---------------- unit: top-45 via 4-pass radix select (NT threads) ----------
// Single-wave 256-bin suffix scan (4 bins/lane, shfl_down Hillis-Steele).
template <int NT>
__device__ void topk_unit(int bh, int t, const float* __restrict__ M,
                          int* __restrict__ Mtop,
                          unsigned* __restrict__ selmap, SmemTopk* s) {
    for (int i = t; i < LL; i += NT) {
        unsigned u = __float_as_uint(M[bh * LL + i]);
        s->keys[i] = (u & 0x80000000u) ? ~u : (u | 0x80000000u);
    }
    if (selmap != nullptr && t < 128) selmap[bh * 128 + t] = 0u;
    if (t == 0) {
        s->sPrefix = 0u; s->sMask = 0u; s->sK = UU;
        s->outCount = 0; s->eqCount = 0;
    }
    __syncthreads();

    for (int pass = 0; pass < 4; ++pass) {
        int shift = 24 - pass * 8;
        if (t < 256) s->hist[t] = 0u;
        __syncthreads();
        unsigned prefix = s->sPrefix, mask = s->sMask;
        for (int i = t; i < LL; i += NT) {
            unsigned k = s->keys[i];
            if ((k & mask) == prefix)
                atomicAdd(&s->hist[(k >> shift) & 0xFFu], 1u);
        }
        __syncthreads();
        if (t < 64) {
            int l = t;
            unsigned h0 = s->hist[4 * l + 0], h1 = s->hist[4 * l + 1];
            unsigned h2 = s->hist[4 * l + 2], h3 = s->hist[4 * l + 3];
            unsigned s3 = h3, s2 = h2 + s3, s1 = h1 + s2, s0 = h0 + s1;
            unsigned tot = s0, inc = tot;
#pragma unroll
            for (int off = 1; off < 64; off <<= 1) {
                unsigned x = __shfl_down(inc, off, 64);
                if (l + off < 64) inc += x;
            }
            unsigned above = inc - tot; // sum over lanes > l
            s->scanbuf[4 * l + 0] = s0 + above;
            s->scanbuf[4 * l + 1] = s1 + above;
            s->scanbuf[4 * l + 2] = s2 + above;
            s->scanbuf[4 * l + 3] = s3 + above;
        }
        __syncthreads();
        if (t < 256) {
            unsigned k = s->sK;
            unsigned geq = s->scanbuf[t];
            unsigned gt = (t < 255) ? s->scanbuf[t + 1] : 0u;
            if (gt < k && geq >= k) s->sBin = (unsigned)t;
        }
        __syncthreads();
        if (t == 0) {
            unsigned b = s->sBin;
            unsigned gt = (b < 255u) ? s->scanbuf[b + 1] : 0u;
            s->sK -= gt;
            s->sPrefix |= (b << shift);
            s->sMask |= (0xFFu << shift);
        }
        __syncthreads();
    }
    unsigned T = s->sPrefix;
    int kEq = (int)s->sK;

    for (int i = t; i < LL; i += NT) {
        unsigned k = s->keys[i];
        if (k > T) {
            int slot = atomicAdd(&s->outCount, 1);
            Mtop[bh * UU + slot] = i;
        } else if (k == T) {
            int e = atomicAdd(&s->eqCount, 1);
            if (e < 64) s->eqIdx[e] = i;
        }
    }
    __syncthreads();

    if (t == 0) {
        int base = s->outCount; // == UU - kEq
        int ec = s->eqCount;
        if (ec <= 64) {
            for (int ss = 0; ss < UU; ++ss) {
                if (ss >= kEq) break;
                int bi = -1, bv = LL + 2;
                for (int j = 0; j < ec; ++j) {
                    int v = s->eqIdx[j];
                    if (v < bv) { bv = v; bi = j; }
                }
                Mtop[bh * UU + base + ss] = bv;
                s->eqIdx[bi] = LL + 2;
            }
        } else {
            int got = 0;
            for (int i = 0; i < LL && got < kEq; ++i)
                if (s->keys[i] == T) { Mtop[bh * UU + base + got] = i; ++got; }
        }
    }
    __syncthreads();
    if (selmap != nullptr && t < UU) {
        int qi = Mtop[bh * UU + t];
        atomicOr(&selmap[bh * 128 + (qi >> 5)], 1u << (qi & 31));
    }
}

// ---------------- unit: split-K flash attention partial (256 threads) --------
__device__ void attn_unit(int bh, int c, int t,
        const float* __restrict__ Q, const float* __restrict__ K,
        const float* __restrict__ V, const int* __restrict__ Mtop,
        float* __restrict__ mPart, float* __restrict__ lPart,
        float* __restrict__ Op, SmemAttn* s) {
    int h = bh % HH, b = bh / HH;
    int k0 = c * CK;

    const size_t rowStride = (size_t)HH * DD; // 512 floats
    const float* Qbh = Q + (size_t)(b * LL * HH + h) * DD;
    const float* Kbh = K + (size_t)(b * LL * HH + h) * DD;
    const float* Vbh = V + (size_t)(b * LL * HH + h) * DD;

    for (int p = t; p < 48 * DD; p += 256) {
        int u = p >> 6, d = p & 63;
        float v = 0.f;
        if (u < UU) {
            int qi = Mtop[bh * UU + u];
            v = Qbh[(size_t)qi * rowStride + d] * 0.125f;
        }
        s->Qs[u * KSTR + d] = v;
    }
    for (int p = t; p < CK * 16; p += 256) {
        int row = p >> 4, i = p & 15;
        *(float4*)&s->Ks[row * KSTR + i * 4] =
            *(const float4*)&Kbh[(size_t)(k0 + row) * rowStride + i * 4];
    }
    __syncthreads();

    // --- scores GEMM: thread tile 3u x 4k ---
    int kq = t & 15, uq = t >> 4;
    int u0 = uq * 3;
    float acc[3][4];
#pragma unroll
    for (int i = 0; i < 3; ++i)
#pragma unroll
        for (int j = 0; j < 4; ++j) acc[i][j] = 0.f;

#pragma unroll 4
    for (int dd = 0; dd < 16; ++dd) {
        float4 qf[3];
#pragma unroll
        for (int i = 0; i < 3; ++i)
            qf[i] = *(const float4*)&s->Qs[(u0 + i) * KSTR + dd * 4];
        float4 kf[4];
#pragma unroll
        for (int j = 0; j < 4; ++j)
            kf[j] = *(const float4*)&s->Ks[(kq + 16 * j) * KSTR + dd * 4];
#pragma unroll
        for (int i = 0; i < 3; ++i)
#pragma unroll
            for (int j = 0; j < 4; ++j) {
                acc[i][j] = fmaf(qf[i].x, kf[j].x, acc[i][j]);
                acc[i][j] = fmaf(qf[i].y, kf[j].y, acc[i][j]);
                acc[i][j] = fmaf(qf[i].z, kf[j].z, acc[i][j]);
                acc[i][j] = fmaf(qf[i].w, kf[j].w, acc[i][j]);
            }
    }
#pragma unroll
    for (int i = 0; i < 3; ++i) {
        int u = u0 + i;
        if (u < UU)
#pragma unroll
            for (int j = 0; j < 4; ++j)
                s->Ss[u * SSTR + kq + 16 * j] = acc[i][j];
    }
    __syncthreads();

    // stage V chunk into the K buffer (no one reads Ks until next barrier)
    for (int p = t; p < CK * 16; p += 256) {
        int row = p >> 4, i = p & 15;
        *(float4*)&s->Ks[row * KSTR + i * 4] =
            *(const float4*)&Vbh[(size_t)(k0 + row) * rowStride + i * 4];
    }

    // --- chunk-local softmax: 4 threads per u ---
    if (t < UU * 4) {
        int u = t >> 2, qq = t & 3;
        float mloc = -INFINITY;
        for (int j = 0; j < CK / 4; ++j)
            mloc = fmaxf(mloc, s->Ss[u * SSTR + qq + 4 * j]);
        mloc = fmaxf(mloc, __shfl_xor(mloc, 1, 64));
        mloc = fmaxf(mloc, __shfl_xor(mloc, 2, 64));
        float lloc = 0.f;
        for (int j = 0; j < CK / 4; ++j) {
            int kk = qq + 4 * j;
            float e = __expf(s->Ss[u * SSTR + kk] - mloc);
            s->Ss[u * SSTR + kk] = e;
            lloc += e;
        }
        lloc += __shfl_xor(lloc, 1, 64);
        lloc += __shfl_xor(lloc, 2, 64);
        if (qq == 0) {
            mPart[(bh * NC + c) * UU + u] = mloc;
            lPart[(bh * NC + c) * UU + u] = lloc;
        }
    }
    __syncthreads();

    // --- PV GEMM: thread tile 3u x 4d ---
    int dq = t & 15;
    int d0 = dq * 4;
    if (u0 < UU) { // uq==15 idle
        float4 o[3];
#pragma unroll
        for (int i = 0; i < 3; ++i) o[i] = make_float4(0.f, 0.f, 0.f, 0.f);
#pragma unroll 4
        for (int kc = 0; kc < CK / 4; ++kc) {
            float4 vk[4];
#pragma unroll
            for (int jj = 0; jj < 4; ++jj)
                vk[jj] = *(const float4*)&s->Ks[(4 * kc + jj) * KSTR + d0];
#pragma unroll
            for (int i = 0; i < 3; ++i) {
                float4 pf = *(const float4*)&s->Ss[(u0 + i) * SSTR + 4 * kc];
                o[i].x = fmaf(pf.x, vk[0].x, o[i].x);
                o[i].y = fmaf(pf.x, vk[0].y, o[i].y);
                o[i].z = fmaf(pf.x, vk[0].z, o[i].z);
                o[i].w = fmaf(pf.x, vk[0].w, o[i].w);
                o[i].x = fmaf(pf.y, vk[1].x, o[i].x);
                o[i].y = fmaf(pf.y, vk[1].y, o[i].y);
                o[i].z = fmaf(pf.y, vk[1].z, o[i].z);
                o[i].w = fmaf(pf.y, vk[1].w, o[i].w);
                o[i].x = fmaf(pf.z, vk[2].x, o[i].x);
                o[i].y = fmaf(pf.z, vk[2].y, o[i].y);
                o[i].z = fmaf(pf.z, vk[2].z, o[i].z);
                o[i].w = fmaf(pf.z, vk[2].w, o[i].w);
                o[i].x = fmaf(pf.w, vk[3].x, o[i].x);
                o[i].y = fmaf(pf.w, vk[3].y, o[i].y);
                o[i].z = fmaf(pf.w, vk[3].z, o[i].z);
                o[i].w = fmaf(pf.w, vk[3].w, o[i].w);
            }
        }
#pragma unroll
        for (int i = 0; i < 3; ++i) {
            int u = u0 + i;
            *(float4*)&Op[((size_t)(bh * NC + c) * UU + u) * DD + d0] = o[i];
        }
    }
}

// ---------------- unit: cumsum tile ------------------------------------------
__device__ void cumsum_unit(int blk, int t, const float* __restrict__ V,
        const float* __restrict__ tsum, const unsigned* __restrict__ selmap,
        float* __restrict__ out, SmemSum* s) {
    int tile = blk % NTILES;
    int bh = blk / NTILES;
    int h = bh % HH, b = bh / HH;
    int d = t & 63, g = t >> 6;
    const int CH = TILE / 4;
    int l0 = tile * TILE + g * CH;

    float acc = 0.f;
    for (int i = 0; i < CH; ++i) acc += V[qkv_idx(b, l0 + i, h, d)];
    s->red[g][d] = acc;
    float p = 0.f;
    for (int tt = g; tt < tile; tt += 4)
        p += tsum[(bh * NTILES + tt) * DD + d];
    s->pre2[g][d] = p;
    __syncthreads();

    float off = s->pre2[0][d] + s->pre2[1][d] + s->pre2[2][d] + s->pre2[3][d];
    for (int gg = 0; gg < g; ++gg) off += s->red[gg][d];

    unsigned selw = (selmap != nullptr) ? selmap[bh * 128 + (l0 >> 5)] : 0u;

    float run = off;
    for (int i = 0; i < CH; ++i) {
        run += V[qkv_idx(b, l0 + i, h, d)];
        if (!((selw >> i) & 1u))
            out[qkv_idx(b, l0 + i, h, d)] = run;
    }
}

// ---------------- unit: flash combine for one (bh,u), 64 threads --------------
__device__ __forceinline__ void combine_unit(
        int u4, int d, const int* __restrict__ Mtop,
        const float* __restrict__ mPart, const float* __restrict__ lPart,
        const float* __restrict__ Op, float* __restrict__ out) {
    int u = u4 % UU;
    int bh = u4 / UU;
    int h = bh % HH, b = bh / HH;
    float gm = -INFINITY;
    for (int c = 0; c < NC; ++c)
        gm = fmaxf(gm, mPart[(bh * NC + c) * UU + u]);
    float denom = 0.f, acc = 0.f;
    for (int c = 0; c < NC; ++c) {
        int pi = (bh * NC + c) * UU + u;
        float w = __expf(mPart[pi] - gm);
        denom = fmaf(lPart[pi], w, denom);
        acc = fmaf(w, Op[(size_t)pi * DD + d], acc);
    }
    int qi = Mtop[bh * UU + u];
    out[qkv_idx(b, qi, h, d)] = acc / denom;
}

// ---------------- Kernel 1: computeM + tilesum (full-grid TLP) ----------------
__global__ __launch_bounds__(256, 2) void k_computeM_tilesum(
        const float* __restrict__ Q, const float* __restrict__ K,
        const int* __restrict__ idx, const float* __restrict__ V,
        float* __restrict__ M, float* __restrict__ tsum) {
    __shared__ float red[4][DD];
    if (blockIdx.x >= NB_CMU) {
        tilesum_unit(blockIdx.x - NB_CMU, threadIdx.x, V, tsum, red);
        return;
    }
    computeM_unit(blockIdx.x * 4 + (threadIdx.x >> 6), threadIdx.x & 63,
                  Q, K, idx, M);
}

// ---------------- Kernel 2 (cooperative): topk -> attn -> cumsum/combine ------
// 768 blocks (3/CU, LDS 42.7KB each) stay resident; cg grid syncs replace two
// kernel-launch gaps. Phase 1 uses 16 blocks; phase 2 1024 units; phase 3 692.
__global__ __launch_bounds__(256, 3) void k_coop(
        const float* __restrict__ Q, const float* __restrict__ K,
        const float* __restrict__ V, const float* __restrict__ M,
        const float* __restrict__ tsum, float* __restrict__ mPart,
        float* __restrict__ lPart, int* __restrict__ Mtop,
        unsigned* __restrict__ selmap, float* __restrict__ Op,
        float* __restrict__ out) {
    cg::grid_group grid = cg::this_grid();
    __shared__ __align__(16) char smem[sizeof(SmemAttn)];
    int t = threadIdx.x;
    int bid = blockIdx.x;

    if (bid < BB * HH)
        topk_unit<256>(bid, t, M, Mtop, selmap, (SmemTopk*)smem);
    grid.sync();

    for (int u = bid; u < BB * HH * NC; u += GRIDB) {
        attn_unit(u / NC, u % NC, t, Q, K, V, Mtop, mPart, lPart, Op,
                  (SmemAttn*)smem);
        __syncthreads(); // protect LDS reuse across loop iterations
    }
    grid.sync();

    for (int u = bid; u < NB_CU + NB_CO; u += GRIDB) {
        if (u < NB_CU)
            cumsum_unit(u, t, V, tsum, selmap, out, (SmemSum*)smem);
        else
            combine_unit((u - NB_CU) * 4 + (t >> 6), t & 63, Mtop, mPart,
                         lPart, Op, out);
    }
}

// ---------------- standalone fallbacks (hedge + compact-ws path) --------------
__global__ __launch_bounds__(1024) void k_topk(
        const float* __restrict__ M, int* __restrict__ Mtop,
        unsigned* __restrict__ selmap) {
    __shared__ SmemTopk s;
    topk_unit<1024>(blockIdx.x, threadIdx.x, M, Mtop, selmap, &s);
}

__global__ __launch_bounds__(256) void k_attn_partial(
        const float* __restrict__ Q, const float* __restrict__ K,
        const float* __restrict__ V, const int* __restrict__ Mtop,
        float* __restrict__ mPart, float* __restrict__ lPart,
        float* __restrict__ Op) {
    __shared__ SmemAttn s;
    attn_unit(blockIdx.x / NC, blockIdx.x % NC, threadIdx.x, Q, K, V, Mtop,
              mPart, lPart, Op, &s);
}

__global__ __launch_bounds__(256) void k_cumsum_combine(
        const float* __restrict__ V, const float* __restrict__ tsum,
        const unsigned* __restrict__ selmap, const int* __restrict__ Mtop,
        const float* __restrict__ mPart, const float* __restrict__ lPart,
        const float* __restrict__ Op, float* __restrict__ out) {
    __shared__ SmemSum s;
    int t = threadIdx.x;
    if (blockIdx.x >= NB_CU) {
        combine_unit((blockIdx.x - NB_CU) * 4 + (t >> 6), t & 63, Mtop,
                     mPart, lPart, Op, out);
        return;
    }
    cumsum_unit(blockIdx.x, t, V, tsum, selmap, out, &s);
}

__global__ __launch_bounds__(256) void k_cumsum_fb(
        const float* __restrict__ V, const float* __restrict__ tsum,
        float* __restrict__ out) {
    __shared__ SmemSum s;
    cumsum_unit(blockIdx.x, threadIdx.x, V, tsum, (const unsigned*)nullptr,
                out, &s);
}

__global__ __launch_bounds__(256) void k_attn_mono(
        const float* __restrict__ Q, const float* __restrict__ K,
        const float* __restrict__ V, const int* __restrict__ Mtop,
        float* __restrict__ out) {
    int blk = blockIdx.x; // bh*UU + u
    int u = blk % UU;
    int bh = blk / UU;
    int h = bh % HH, b = bh / HH;
    int qi = Mtop[bh * UU + u];
    int t = threadIdx.x;

    __shared__ float scores[LL];
    __shared__ float red[256];

    const float4* qp = (const float4*)(Q + qkv_idx(b, qi, h, 0));
    float4 qreg[16];
#pragma unroll
    for (int i = 0; i < 16; ++i) {
        float4 v = qp[i];
        v.x *= 0.125f; v.y *= 0.125f; v.z *= 0.125f; v.w *= 0.125f;
        qreg[i] = v;
    }

    float lmax = -INFINITY;
    for (int k = t; k < LL; k += 256) {
        const float4* kr = (const float4*)(K + qkv_idx(b, k, h, 0));
        float dot = 0.f;
#pragma unroll
        for (int i = 0; i < 16; ++i) {
            float4 kk = kr[i];
            dot = fmaf(qreg[i].x, kk.x, dot);
            dot = fmaf(qreg[i].y, kk.y, dot);
            dot = fmaf(qreg[i].z, kk.z, dot);
            dot = fmaf(qreg[i].w, kk.w, dot);
        }
        scores[k] = dot;
        lmax = fmaxf(lmax, dot);
    }
    red[t] = lmax;
    __syncthreads();
    for (int off = 128; off >= 1; off >>= 1) {
        if (t < off) red[t] = fmaxf(red[t], red[t + off]);
        __syncthreads();
    }
    float smax = red[0];
    __syncthreads();

    float lsum = 0.f;
    for (int k = t; k < LL; k += 256) {
        float e = __expf(scores[k] - smax);
        scores[k] = e;
        lsum += e;
    }
    red[t] = lsum;
    __syncthreads();
    for (int off = 128; off >= 1; off >>= 1) {
        if (t < off) red[t] += red[t + off];
        __syncthreads();
    }
    float denom = red[0];
    __syncthreads();

    int d = t & 63, g = t >> 6;
    const float4* sc4 = (const float4*)scores;
    float acc = 0.f;
    for (int kb = g; kb < LL / 4; kb += 4) {
        float4 s4 = sc4[kb];
        int kk0 = kb * 4;
        acc = fmaf(s4.x, V[qkv_idx(b, kk0 + 0, h, d)], acc);
        acc = fmaf(s4.y, V[qkv_idx(b, kk0 + 1, h, d)], acc);
        acc = fmaf(s4.z, V[qkv_idx(b, kk0 + 2, h, d)], acc);
        acc = fmaf(s4.w, V[qkv_idx(b, kk0 + 3, h, d)], acc);
    }
    red[t] = acc;
    __syncthreads();
    if (g == 0) {
        float s = red[d] + red[64 + d] + red[128 + d] + red[192 + d];
        out[qkv_idx(b, qi, h, d)] = s / denom;
    }
}

extern "C" void kernel_launch(void* const* d_in, const int* in_sizes, int n_in,
                              void* d_out, int out_size, void* d_ws, size_t ws_size,
                              hipStream_t stream) {
    const float* Q = (const float*)d_in[0];
    const float* K = (const float*)d_in[1];
    const float* V = (const float*)d_in[2];
    const int* idx = (const int*)d_in[3];
    float* out = (float*)d_out;

    float* ws = (float*)d_ws;

    // workspace layout (floats)
    const size_t M_off = 0;                           // 65536
    const size_t tsum_off = 65536;                    // 32768
    const size_t mP_off = 98304;                      // 16*64*45 = 46080
    const size_t lP_off = 144384;                     // 46080
    const size_t top_off = 190464;                    // 720 ints (reserve 1024)
    const size_t sel_off = 191488;                    // 16*128 uints (2048)
    const size_t Op_off = 193536;                     // 16*64*45*64 = 2949120
    const size_t need = (Op_off + (size_t)BB * HH * NC * UU * DD) * 4;

    float* M = ws + M_off;
    float* tsum = ws + tsum_off;

    if (ws_size >= need) {
        float* mPart = ws + mP_off;
        float* lPart = ws + lP_off;
        int* Mtop = (int*)(ws + top_off);
        unsigned* selmap = (unsigned*)(ws + sel_off);
        float* Op = ws + Op_off;

        k_computeM_tilesum<<<NB_CMU + NB_TS, 256, 0, stream>>>(Q, K, idx, V,
                                                               M, tsum);

        void* kargs[] = {(void*)&Q, (void*)&K, (void*)&V, (void*)&M,
                         (void*)&tsum, (void*)&mPart, (void*)&lPart,
                         (void*)&Mtop, (void*)&selmap, (void*)&Op,
                         (void*)&out};
        hipError_t ce = hipLaunchCooperativeKernel(
            (void*)k_coop, dim3(GRIDB), dim3(256), kargs, 0, stream);
        if (ce != hipSuccess) {
            // hedge: cooperative launch rejected (e.g. capture) -> proven path
            k_topk<<<BB * HH, 1024, 0, stream>>>(M, Mtop, selmap);
            k_attn_partial<<<BB * HH * NC, 256, 0, stream>>>(Q, K, V, Mtop,
                                                             mPart, lPart, Op);
            k_cumsum_combine<<<NB_CU + NB_CO, 256, 0, stream>>>(
                V, tsum, selmap, Mtop, mPart, lPart, Op, out);
        }
    } else {
        // compact fallback layout
        int* Mtop = (int*)(ws + 65536);
        float* tsum2 = ws + 65536 + 1024;
        k_computeM_tilesum<<<NB_CMU + NB_TS, 256, 0, stream>>>(Q, K, idx, V,
                                                               M, tsum2);
        k_topk<<<BB * HH, 1024, 0, stream>>>(M, Mtop, (unsigned*)nullptr);
        k_cumsum_fb<<<BB * HH * NTILES, 256, 0, stream>>>(V, tsum2, out);
        k_attn_mono<<<BB * HH * UU, 256, 0, stream>>>(Q, K, V, Mtop, out);
    }
}

// Round 15
// 283.390 us; speedup vs baseline: 1.1347x; 1.1347x over previous
//
#include <hip/hip_runtime.h>
#include <math.h>

#define BB 2
#define LL 4096
#define HH 8
#define DD 64
#define UU 45
#define TILE 128
#define NTILES (LL / TILE) // 32

// split-K attention config
#define NC 64              // key chunks
#define CK (LL / NC)       // 64 keys per chunk
#define KSTR 68            // padded LDS row stride (floats) for K/V/Q tiles
#define SSTR 68            // padded LDS row stride for scores (CK=64 + 4)

#define NB_CMU (BB * HH * LL / 4)  // 16384 computeM blocks (4 queries each)
#define NB_TS (BB * HH * NTILES)   // 512 tilesum blocks
#define NB_AT (BB * HH * NC)       // 1024 attn blocks
#define NB_CU (BB * HH * NTILES)   // 512 cumsum blocks
#define NB_CO (BB * HH * UU / 4)   // 180 combine blocks (4 u's each)

#define TBINS 4096
#define TSHIFT 20

__device__ __forceinline__ int qkv_idx(int b, int l, int h, int d) {
    return ((b * LL + l) * HH + h) * DD + d;
}

// DPP all-reduce helper: v += rotate-within-16-lane-row(v, N). VALU pipe only.
template <int CTRL>
__device__ __forceinline__ float dpp_add(float v) {
    int x = __builtin_amdgcn_update_dpp(0, __float_as_int(v), CTRL, 0xF, 0xF,
                                        true);
    return v + __int_as_float(x);
}

// ---------------- shared-memory overlays -------------------------------------
struct SmemAttn {
    float Qs[48 * KSTR];     // 13056 B
    float Ks[CK * KSTR];     // 17408 B (reused for V in PV phase)
    float Ss[UU * SSTR];     // 12240 B
};
struct SmemSum {
    float red[4][DD];
    float pre2[4][DD];
};

// ---------------- unit: sparsity metric M for one query (one wave) -----------
// 16 lanes per sampled K row (4 contiguous 256B runs per load -- segment-
// optimal). Rounds 7-10 established: this is TA/L2-gather-throughput bound at
// ~50us (805MB gather at ~16TB/s effective); load batching (array /
// launch-bounds / sched_barrier / inline-asm) is mechanism-refuted.
__device__ __forceinline__ void computeM_unit(
        int w, int lane, const float* __restrict__ Q,
        const float* __restrict__ K, const int* __restrict__ idx,
        float* __restrict__ M) {
    int q = w % LL;
    int bh = w / LL;            // b*HH + h
    int h = bh % HH, b = bh / HH;

    const float* Kbh = K + (size_t)(b * LL * HH + h) * DD;
    const size_t rowStride = (size_t)HH * DD; // 512 floats between key rows

    int r = lane >> 4;    // which of 4 rows this lane helps load (DPP row id)
    int c16 = lane & 15;  // position within 16-lane row group

    const float4 qf = *(const float4*)(Q + qkv_idx(b, q, h, c16 * 4));
    const int* idxRow = idx + q * UU;

    int ks[12];
#pragma unroll
    for (int g = 0; g < 12; ++g) {
        int s = g * 4 + r;
        ks[g] = idxRow[s < UU ? s : 0];  // clamped (row-end OOB guard)
    }
    float4 kk[12];
#pragma unroll
    for (int g = 0; g < 12; ++g)
        kk[g] = ((const float4*)(Kbh + (size_t)ks[g] * rowStride))[c16];

    float mval = -INFINITY, sval = 0.f;
#pragma unroll
    for (int g = 0; g < 12; ++g) {
        float part = fmaf(kk[g].x, qf.x,
                     fmaf(kk[g].y, qf.y,
                     fmaf(kk[g].z, qf.z, kk[g].w * qf.w)));
        part = dpp_add<0x128>(part); // row_ror:8
        part = dpp_add<0x124>(part); // row_ror:4
        part = dpp_add<0x122>(part); // row_ror:2
        part = dpp_add<0x121>(part); // row_ror:1
        int s = g * 4 + r;
        if (s < UU) { mval = fmaxf(mval, part); sval += part; }
    }
    mval = fmaxf(mval, __shfl_xor(mval, 16, 64));
    sval += __shfl_xor(sval, 16, 64);
    mval = fmaxf(mval, __shfl_xor(mval, 32, 64));
    sval += __shfl_xor(sval, 32, 64);
    if (lane == 0) M[bh * LL + q] = mval - sval * (1.0f / LL);
}

// ---------------- Kernel 1: computeM + tilesum (full-grid TLP) ----------------
__global__ __launch_bounds__(256, 2) void k_computeM_tilesum(
        const float* __restrict__ Q, const float* __restrict__ K,
        const int* __restrict__ idx, const float* __restrict__ V,
        float* __restrict__ M, float* __restrict__ tsum) {
    if (blockIdx.x >= NB_CMU) {
        // ---- tilesum branch ----
        int blk = blockIdx.x - NB_CMU; // ((b*HH+h)*NTILES + tile)
        int tile = blk % NTILES;
        int bh = blk / NTILES;
        int h = bh % HH, b = bh / HH;
        int d = threadIdx.x & 63, g = threadIdx.x >> 6; // g in 0..3
        const int CH = TILE / 4;                        // 32
        int l0 = tile * TILE + g * CH;
        float acc = 0.f;
        for (int i = 0; i < CH; ++i) acc += V[qkv_idx(b, l0 + i, h, d)];
        __shared__ float red[4][DD];
        red[g][d] = acc;
        __syncthreads();
        if (g == 0)
            tsum[blk * DD + d] =
                red[0][d] + red[1][d] + red[2][d] + red[3][d];
        return;
    }
    computeM_unit(blockIdx.x * 4 + (threadIdx.x >> 6), threadIdx.x & 63,
                  Q, K, idx, M);
}

// ---------------- Kernel 2: top-45 via SINGLE 12-bit radix pass ---------------
// 16 blocks x 1024 threads, latency-bound (no TLP to hide barriers) -- so the
// round-12 change is pass-count: ONE 4096-bin histogram + one block suffix-
// scan replaces 4x(256-bin histogram+scan). Boundary bin holds ~1 key on
// random data; exact within-bin selection (value desc, index asc = reference
// tie semantics) over a <=64-entry list; serial fallback for mass ties.
__global__ __launch_bounds__(1024) void k_topk(
        const float* __restrict__ M, int* __restrict__ Mtop,
        unsigned* __restrict__ selmap) {
    int bh = blockIdx.x;
    int t = threadIdx.x;
    __shared__ unsigned keys[LL];      // 16 KB
    __shared__ unsigned geq[TBINS];    // 16 KB: hist, then in-place suffix scan
    __shared__ unsigned wsum[16];
    __shared__ unsigned sB, sNgt;
    __shared__ int outCount, eqCount;
    __shared__ unsigned eqKey[64];
    __shared__ int eqIdx[64];

    for (int i = t; i < LL; i += 1024) {
        unsigned u = __float_as_uint(M[bh * LL + i]);
        keys[i] = (u & 0x80000000u) ? ~u : (u | 0x80000000u);
    }
    for (int i = t; i < TBINS; i += 1024) geq[i] = 0u;
    if (selmap != nullptr && t < 128) selmap[bh * 128 + t] = 0u;
    if (t == 0) { outCount = 0; eqCount = 0; }
    __syncthreads();

    for (int i = t; i < LL; i += 1024)
        atomicAdd(&geq[keys[i] >> TSHIFT], 1u);
    __syncthreads();

    // block-wide suffix scan over 4096 bins: thread t owns bins 4t..4t+3
    int lane = t & 63, wv = t >> 6;
    unsigned h0 = geq[4 * t + 0], h1 = geq[4 * t + 1];
    unsigned h2 = geq[4 * t + 2], h3 = geq[4 * t + 3];
    unsigned s3 = h3, s2 = h2 + s3, s1 = h1 + s2, s0 = h0 + s1;
    unsigned tot = s0, inc = tot;
#pragma unroll
    for (int off = 1; off < 64; off <<= 1) {
        unsigned x = __shfl_down(inc, off, 64);
        if (lane + off < 64) inc += x;
    }
    if (lane == 0) wsum[wv] = inc;
    __syncthreads();
    unsigned above = inc - tot;             // lanes > me within wave
    for (int w2 = wv + 1; w2 < 16; ++w2) above += wsum[w2];
    geq[4 * t + 0] = s0 + above;
    geq[4 * t + 1] = s1 + above;
    geq[4 * t + 2] = s2 + above;
    geq[4 * t + 3] = s3 + above;
    __syncthreads();
    // boundary bin: unique b with geq[b+1] < UU <= geq[b]
#pragma unroll
    for (int j = 0; j < 4; ++j) {
        int b2 = 4 * t + j;
        unsigned g = geq[b2];
        unsigned gn = (b2 < TBINS - 1) ? geq[b2 + 1] : 0u;
        if (gn < UU && g >= UU) { sB = (unsigned)b2; sNgt = gn; }
    }
    __syncthreads();
    unsigned B = sB;
    int kEq = UU - (int)sNgt;

    for (int i = t; i < LL; i += 1024) {
        unsigned k = keys[i];
        unsigned b2 = k >> TSHIFT;
        if (b2 > B) {
            int slot = atomicAdd(&outCount, 1);
            Mtop[bh * UU + slot] = i;
        } else if (b2 == B) {
            int e = atomicAdd(&eqCount, 1);
            if (e < 64) { eqKey[e] = k; eqIdx[e] = i; }
        }
    }
    __syncthreads();

    if (t == 0) {
        int base = outCount; // == sNgt
        int ec = eqCount;
        if (ec <= 64) {
            for (int s = 0; s < kEq; ++s) {
                int bi = -1, bidx = LL + 2;
                unsigned bk = 0u;
                for (int j = 0; j < ec; ++j) {
                    if (eqIdx[j] < 0) continue;
                    unsigned kj = eqKey[j];
                    if (bi < 0 || kj > bk || (kj == bk && eqIdx[j] < bidx)) {
                        bi = j; bk = kj; bidx = eqIdx[j];
                    }
                }
                Mtop[bh * UU + base + s] = bidx;
                eqIdx[bi] = -1;
            }
        } else {
            // paranoid fallback (mass ties in one bin): serial exact select
            unsigned mark = (B == TBINS - 1) ? 0u : 0xFFFFFFFFu; // bin != B
            for (int s = 0; s < kEq; ++s) {
                unsigned bk = 0u;
                int bidx = -1;
                for (int i = 0; i < LL; ++i) {
                    unsigned k = keys[i];
                    if ((k >> TSHIFT) == B &&
                        (bidx < 0 || k > bk)) { bk = k; bidx = i; }
                }
                Mtop[bh * UU + base + s] = bidx;
                keys[bidx] = mark;
            }
        }
    }
    __syncthreads();
    if (selmap != nullptr && t < UU) {
        int qi = Mtop[bh * UU + t];
        atomicOr(&selmap[bh * 128 + (qi >> 5)], 1u << (qi & 31));
    }
}

// ---------------- unit: split-K flash attention partial (256 threads) --------
__device__ void attn_unit(int bh, int c, int t,
        const float* __restrict__ Q, const float* __restrict__ K,
        const float* __restrict__ V, const int* __restrict__ Mtop,
        float* __restrict__ mPart, float* __restrict__ lPart,
        float* __restrict__ Op, SmemAttn* s) {
    int h = bh % HH, b = bh / HH;
    int k0 = c * CK;

    const size_t rowStride = (size_t)HH * DD; // 512 floats
    const float* Qbh = Q + (size_t)(b * LL * HH + h) * DD;
    const float* Kbh = K + (size_t)(b * LL * HH + h) * DD;
    const float* Vbh = V + (size_t)(b * LL * HH + h) * DD;

    for (int p = t; p < 48 * DD; p += 256) {
        int u = p >> 6, d = p & 63;
        float v = 0.f;
        if (u < UU) {
            int qi = Mtop[bh * UU + u];
            v = Qbh[(size_t)qi * rowStride + d] * 0.125f;
        }
        s->Qs[u * KSTR + d] = v;
    }
    for (int p = t; p < CK * 16; p += 256) {
        int row = p >> 4, i = p & 15;
        *(float4*)&s->Ks[row * KSTR + i * 4] =
            *(const float4*)&Kbh[(size_t)(k0 + row) * rowStride + i * 4];
    }
    __syncthreads();

    // --- scores GEMM: thread tile 3u x 4k ---
    int kq = t & 15, uq = t >> 4;
    int u0 = uq * 3;
    float acc[3][4];
#pragma unroll
    for (int i = 0; i < 3; ++i)
#pragma unroll
        for (int j = 0; j < 4; ++j) acc[i][j] = 0.f;

#pragma unroll 4
    for (int dd = 0; dd < 16; ++dd) {
        float4 qf[3];
#pragma unroll
        for (int i = 0; i < 3; ++i)
            qf[i] = *(const float4*)&s->Qs[(u0 + i) * KSTR + dd * 4];
        float4 kf[4];
#pragma unroll
        for (int j = 0; j < 4; ++j)
            kf[j] = *(const float4*)&s->Ks[(kq + 16 * j) * KSTR + dd * 4];
#pragma unroll
        for (int i = 0; i < 3; ++i)
#pragma unroll
            for (int j = 0; j < 4; ++j) {
                acc[i][j] = fmaf(qf[i].x, kf[j].x, acc[i][j]);
                acc[i][j] = fmaf(qf[i].y, kf[j].y, acc[i][j]);
                acc[i][j] = fmaf(qf[i].z, kf[j].z, acc[i][j]);
                acc[i][j] = fmaf(qf[i].w, kf[j].w, acc[i][j]);
            }
    }
#pragma unroll
    for (int i = 0; i < 3; ++i) {
        int u = u0 + i;
        if (u < UU)
#pragma unroll
            for (int j = 0; j < 4; ++j)
                s->Ss[u * SSTR + kq + 16 * j] = acc[i][j];
    }
    __syncthreads();

    // stage V chunk into the K buffer (no one reads Ks until next barrier)
    for (int p = t; p < CK * 16; p += 256) {
        int row = p >> 4, i = p & 15;
        *(float4*)&s->Ks[row * KSTR + i * 4] =
            *(const float4*)&Vbh[(size_t)(k0 + row) * rowStride + i * 4];
    }

    // --- chunk-local softmax: 4 threads per u ---
    if (t < UU * 4) {
        int u = t >> 2, qq = t & 3;
        float mloc = -INFINITY;
        for (int j = 0; j < CK / 4; ++j)
            mloc = fmaxf(mloc, s->Ss[u * SSTR + qq + 4 * j]);
        mloc = fmaxf(mloc, __shfl_xor(mloc, 1, 64));
        mloc = fmaxf(mloc, __shfl_xor(mloc, 2, 64));
        float lloc = 0.f;
        for (int j = 0; j < CK / 4; ++j) {
            int kk = qq + 4 * j;
            float e = __expf(s->Ss[u * SSTR + kk] - mloc);
            s->Ss[u * SSTR + kk] = e;
            lloc += e;
        }
        lloc += __shfl_xor(lloc, 1, 64);
        lloc += __shfl_xor(lloc, 2, 64);
        if (qq == 0) {
            mPart[(bh * NC + c) * UU + u] = mloc;
            lPart[(bh * NC + c) * UU + u] = lloc;
        }
    }
    __syncthreads();

    // --- PV GEMM: thread tile 3u x 4d ---
    int dq = t & 15;
    int d0 = dq * 4;
    if (u0 < UU) { // uq==15 idle
        float4 o[3];
#pragma unroll
        for (int i = 0; i < 3; ++i) o[i] = make_float4(0.f, 0.f, 0.f, 0.f);
#pragma unroll 4
        for (int kc = 0; kc < CK / 4; ++kc) {
            float4 vk[4];
#pragma unroll
            for (int jj = 0; jj < 4; ++jj)
                vk[jj] = *(const float4*)&s->Ks[(4 * kc + jj) * KSTR + d0];
#pragma unroll
            for (int i = 0; i < 3; ++i) {
                float4 pf = *(const float4*)&s->Ss[(u0 + i) * SSTR + 4 * kc];
                o[i].x = fmaf(pf.x, vk[0].x, o[i].x);
                o[i].y = fmaf(pf.x, vk[0].y, o[i].y);
                o[i].z = fmaf(pf.x, vk[0].z, o[i].z);
                o[i].w = fmaf(pf.x, vk[0].w, o[i].w);
                o[i].x = fmaf(pf.y, vk[1].x, o[i].x);
                o[i].y = fmaf(pf.y, vk[1].y, o[i].y);
                o[i].z = fmaf(pf.y, vk[1].z, o[i].z);
                o[i].w = fmaf(pf.y, vk[1].w, o[i].w);
                o[i].x = fmaf(pf.z, vk[2].x, o[i].x);
                o[i].y = fmaf(pf.z, vk[2].y, o[i].y);
                o[i].z = fmaf(pf.z, vk[2].z, o[i].z);
                o[i].w = fmaf(pf.z, vk[2].w, o[i].w);
                o[i].x = fmaf(pf.w, vk[3].x, o[i].x);
                o[i].y = fmaf(pf.w, vk[3].y, o[i].y);
                o[i].z = fmaf(pf.w, vk[3].z, o[i].z);
                o[i].w = fmaf(pf.w, vk[3].w, o[i].w);
            }
        }
#pragma unroll
        for (int i = 0; i < 3; ++i) {
            int u = u0 + i;
            *(float4*)&Op[((size_t)(bh * NC + c) * UU + u) * DD + d0] = o[i];
        }
    }
}

// ---------------- unit: cumsum tile ------------------------------------------
__device__ void cumsum_unit(int blk, int t, const float* __restrict__ V,
        const float* __restrict__ tsum, const unsigned* __restrict__ selmap,
        float* __restrict__ out, SmemSum* s) {
    int tile = blk % NTILES;
    int bh = blk / NTILES;
    int h = bh % HH, b = bh / HH;
    int d = t & 63, g = t >> 6;
    const int CH = TILE / 4;
    int l0 = tile * TILE + g * CH;

    float acc = 0.f;
    for (int i = 0; i < CH; ++i) acc += V[qkv_idx(b, l0 + i, h, d)];
    s->red[g][d] = acc;
    float p = 0.f;
    for (int tt = g; tt < tile; tt += 4)
        p += tsum[(bh * NTILES + tt) * DD + d];
    s->pre2[g][d] = p;
    __syncthreads();

    float off = s->pre2[0][d] + s->pre2[1][d] + s->pre2[2][d] + s->pre2[3][d];
    for (int gg = 0; gg < g; ++gg) off += s->red[gg][d];

    unsigned selw = (selmap != nullptr) ? selmap[bh * 128 + (l0 >> 5)] : 0u;

    float run = off;
    for (int i = 0; i < CH; ++i) {
        run += V[qkv_idx(b, l0 + i, h, d)];
        if (!((selw >> i) & 1u))
            out[qkv_idx(b, l0 + i, h, d)] = run;
    }
}

// ---------------- Kernel 3: attn partials ∥ cumsum (independent given topk) ---
// cumsum depends only on selmap+tsum, not on attn -- appending its 512 blocks
// to attn's 1024 lets the two overlap (same-stream kernels serialize, so this
// is the only way). Both write disjoint out rows vs k_combine.
__global__ __launch_bounds__(256) void k_attn_cumsum(
        const float* __restrict__ Q, const float* __restrict__ K,
        const float* __restrict__ V, const int* __restrict__ Mtop,
        const float* __restrict__ tsum, const unsigned* __restrict__ selmap,
        float* __restrict__ mPart, float* __restrict__ lPart,
        float* __restrict__ Op, float* __restrict__ out) {
    __shared__ __align__(16) char smem[sizeof(SmemAttn)];
    if (blockIdx.x < NB_AT)
        attn_unit(blockIdx.x / NC, blockIdx.x % NC, threadIdx.x, Q, K, V,
                  Mtop, mPart, lPart, Op, (SmemAttn*)smem);
    else
        cumsum_unit(blockIdx.x - NB_AT, threadIdx.x, V, tsum, selmap, out,
                    (SmemSum*)smem);
}

// ---------------- Kernel 4: flash combine across chunks, scatter --------------
__global__ void k_combine(
        const int* __restrict__ Mtop, const float* __restrict__ mPart,
        const float* __restrict__ lPart, const float* __restrict__ Op,
        float* __restrict__ out) {
    int t = threadIdx.x;
    int u4 = blockIdx.x * 4 + (t >> 6); // 0..719
    int u = u4 % UU;
    int bh = u4 / UU;
    int h = bh % HH, b = bh / HH;
    int d = t & 63;
    float gm = -INFINITY;
    for (int c = 0; c < NC; ++c)
        gm = fmaxf(gm, mPart[(bh * NC + c) * UU + u]);
    float denom = 0.f, acc = 0.f;
    for (int c = 0; c < NC; ++c) {
        int pi = (bh * NC + c) * UU + u;
        float w = __expf(mPart[pi] - gm);
        denom = fmaf(lPart[pi], w, denom);
        acc = fmaf(w, Op[(size_t)pi * DD + d], acc);
    }
    int qi = Mtop[bh * UU + u];
    out[qkv_idx(b, qi, h, d)] = acc / denom;
}

// ---------------- fallbacks (compact-ws path) ---------------------------------
__global__ __launch_bounds__(256) void k_cumsum_fb(
        const float* __restrict__ V, const float* __restrict__ tsum,
        float* __restrict__ out) {
    __shared__ SmemSum s;
    cumsum_unit(blockIdx.x, threadIdx.x, V, tsum, (const unsigned*)nullptr,
                out, &s);
}

__global__ __launch_bounds__(256) void k_attn_mono(
        const float* __restrict__ Q, const float* __restrict__ K,
        const float* __restrict__ V, const int* __restrict__ Mtop,
        float* __restrict__ out) {
    int blk = blockIdx.x; // bh*UU + u
    int u = blk % UU;
    int bh = blk / UU;
    int h = bh % HH, b = bh / HH;
    int qi = Mtop[bh * UU + u];
    int t = threadIdx.x;

    __shared__ float scores[LL];
    __shared__ float red[256];

    const float4* qp = (const float4*)(Q + qkv_idx(b, qi, h, 0));
    float4 qreg[16];
#pragma unroll
    for (int i = 0; i < 16; ++i) {
        float4 v = qp[i];
        v.x *= 0.125f; v.y *= 0.125f; v.z *= 0.125f; v.w *= 0.125f;
        qreg[i] = v;
    }

    float lmax = -INFINITY;
    for (int k = t; k < LL; k += 256) {
        const float4* kr = (const float4*)(K + qkv_idx(b, k, h, 0));
        float dot = 0.f;
#pragma unroll
        for (int i = 0; i < 16; ++i) {
            float4 kk = kr[i];
            dot = fmaf(qreg[i].x, kk.x, dot);
            dot = fmaf(qreg[i].y, kk.y, dot);
            dot = fmaf(qreg[i].z, kk.z, dot);
            dot = fmaf(qreg[i].w, kk.w, dot);
        }
        scores[k] = dot;
        lmax = fmaxf(lmax, dot);
    }
    red[t] = lmax;
    __syncthreads();
    for (int off = 128; off >= 1; off >>= 1) {
        if (t < off) red[t] = fmaxf(red[t], red[t + off]);
        __syncthreads();
    }
    float smax = red[0];
    __syncthreads();

    float lsum = 0.f;
    for (int k = t; k < LL; k += 256) {
        float e = __expf(scores[k] - smax);
        scores[k] = e;
        lsum += e;
    }
    red[t] = lsum;
    __syncthreads();
    for (int off = 128; off >= 1; off >>= 1) {
        if (t < off) red[t] += red[t + off];
        __syncthreads();
    }
    float denom = red[0];
    __syncthreads();

    int d = t & 63, g = t >> 6;
    const float4* sc4 = (const float4*)scores;
    float acc = 0.f;
    for (int kb = g; kb < LL / 4; kb += 4) {
        float4 s4 = sc4[kb];
        int kk0 = kb * 4;
        acc = fmaf(s4.x, V[qkv_idx(b, kk0 + 0, h, d)], acc);
        acc = fmaf(s4.y, V[qkv_idx(b, kk0 + 1, h, d)], acc);
        acc = fmaf(s4.z, V[qkv_idx(b, kk0 + 2, h, d)], acc);
        acc = fmaf(s4.w, V[qkv_idx(b, kk0 + 3, h, d)], acc);
    }
    red[t] = acc;
    __syncthreads();
    if (g == 0) {
        float s = red[d] + red[64 + d] + red[128 + d] + red[192 + d];
        out[qkv_idx(b, qi, h, d)] = s / denom;
    }
}

extern "C" void kernel_launch(void* const* d_in, const int* in_sizes, int n_in,
                              void* d_out, int out_size, void* d_ws, size_t ws_size,
                              hipStream_t stream) {
    const float* Q = (const float*)d_in[0];
    const float* K = (const float*)d_in[1];
    const float* V = (const float*)d_in[2];
    const int* idx = (const int*)d_in[3];
    float* out = (float*)d_out;

    float* ws = (float*)d_ws;

    // workspace layout (floats)
    const size_t M_off = 0;                           // 65536
    const size_t tsum_off = 65536;                    // 32768
    const size_t mP_off = 98304;                      // 16*64*45 = 46080
    const size_t lP_off = 144384;                     // 46080
    const size_t top_off = 190464;                    // 720 ints (reserve 1024)
    const size_t sel_off = 191488;                    // 16*128 uints (2048)
    const size_t Op_off = 193536;                     // 16*64*45*64 = 2949120
    const size_t need = (Op_off + (size_t)BB * HH * NC * UU * DD) * 4;

    float* M = ws + M_off;
    float* tsum = ws + tsum_off;

    if (ws_size >= need) {
        float* mPart = ws + mP_off;
        float* lPart = ws + lP_off;
        int* Mtop = (int*)(ws + top_off);
        unsigned* selmap = (unsigned*)(ws + sel_off);
        float* Op = ws + Op_off;

        k_computeM_tilesum<<<NB_CMU + NB_TS, 256, 0, stream>>>(Q, K, idx, V,
                                                               M, tsum);
        k_topk<<<BB * HH, 1024, 0, stream>>>(M, Mtop, selmap);
        k_attn_cumsum<<<NB_AT + NB_CU, 256, 0, stream>>>(
            Q, K, V, Mtop, tsum, selmap, mPart, lPart, Op, out);
        k_combine<<<NB_CO, 256, 0, stream>>>(Mtop, mPart, lPart, Op, out);
    } else {
        // compact fallback layout
        int* Mtop = (int*)(ws + 65536);
        float* tsum2 = ws + 65536 + 1024;
        k_computeM_tilesum<<<NB_CMU + NB_TS, 256, 0, stream>>>(Q, K, idx, V,
                                                               M, tsum2);
        k_topk<<<BB * HH, 1024, 0, stream>>>(M, Mtop, (unsigned*)nullptr);
        k_cumsum_fb<<<BB * HH * NTILES, 256, 0, stream>>>(V, tsum2, out);
        k_attn_mono<<<BB * HH * UU, 256, 0, stream>>>(Q, K, V, Mtop, out);
    }
}

// Round 16
// 185.181 us; speedup vs baseline: 1.7365x; 1.5303x over previous
//
#include <hip/hip_runtime.h>
#include <math.h>

#define BB 2
#define LL 4096
#define HH 8
#define DD 64
#define UU 45
#define TILE 128
#define NTILES (LL / TILE) // 32

// split-K attention config
#define NC 64              // key chunks
#define CK (LL / NC)       // 64 keys per chunk
#define KSTR 68            // padded LDS row stride (floats) for K/V/Q tiles
#define SSTR 68            // padded LDS row stride for scores (CK=64 + 4)

#define NB_CMU (BB * HH * LL / 4)  // 16384 computeM blocks (4 queries each)
#define NB_TS (BB * HH * NTILES)   // 512 tilesum blocks
#define NB_AT (BB * HH * NC)       // 1024 attn blocks
#define NB_CU (BB * HH * NTILES)   // 512 cumsum blocks
#define NB_CO (BB * HH * UU / 4)   // 180 combine blocks (4 u's each)

__device__ __forceinline__ int qkv_idx(int b, int l, int h, int d) {
    return ((b * LL + l) * HH + h) * DD + d;
}

// DPP all-reduce helper: v += rotate-within-16-lane-row(v, N). VALU pipe only.
template <int CTRL>
__device__ __forceinline__ float dpp_add(float v) {
    int x = __builtin_amdgcn_update_dpp(0, __float_as_int(v), CTRL, 0xF, 0xF,
                                        true);
    return v + __int_as_float(x);
}

// ---------------- shared-memory overlays -------------------------------------
struct SmemAttn {
    float Qs[48 * KSTR];     // 13056 B
    float Ks[CK * KSTR];     // 17408 B (reused for V in PV phase)
    float Ss[UU * SSTR];     // 12240 B
};
struct SmemSum {
    float red[4][DD];
    float pre2[4][DD];
};

// ---------------- unit: sparsity metric M for one query (one wave) -----------
// 16 lanes per sampled K row (4 contiguous 256B runs per load -- segment-
// optimal). Rounds 7-10 established: this is TA/L2-gather-throughput bound at
// ~50us (805MB gather at ~16TB/s effective); load batching (array /
// launch-bounds / sched_barrier / inline-asm) is mechanism-refuted.
__device__ __forceinline__ void computeM_unit(
        int w, int lane, const float* __restrict__ Q,
        const float* __restrict__ K, const int* __restrict__ idx,
        float* __restrict__ M) {
    int q = w % LL;
    int bh = w / LL;            // b*HH + h
    int h = bh % HH, b = bh / HH;

    const float* Kbh = K + (size_t)(b * LL * HH + h) * DD;
    const size_t rowStride = (size_t)HH * DD; // 512 floats between key rows

    int r = lane >> 4;    // which of 4 rows this lane helps load (DPP row id)
    int c16 = lane & 15;  // position within 16-lane row group

    const float4 qf = *(const float4*)(Q + qkv_idx(b, q, h, c16 * 4));
    const int* idxRow = idx + q * UU;

    int ks[12];
#pragma unroll
    for (int g = 0; g < 12; ++g) {
        int s = g * 4 + r;
        ks[g] = idxRow[s < UU ? s : 0];  // clamped (row-end OOB guard)
    }
    float4 kk[12];
#pragma unroll
    for (int g = 0; g < 12; ++g)
        kk[g] = ((const float4*)(Kbh + (size_t)ks[g] * rowStride))[c16];

    float mval = -INFINITY, sval = 0.f;
#pragma unroll
    for (int g = 0; g < 12; ++g) {
        float part = fmaf(kk[g].x, qf.x,
                     fmaf(kk[g].y, qf.y,
                     fmaf(kk[g].z, qf.z, kk[g].w * qf.w)));
        part = dpp_add<0x128>(part); // row_ror:8
        part = dpp_add<0x124>(part); // row_ror:4
        part = dpp_add<0x122>(part); // row_ror:2
        part = dpp_add<0x121>(part); // row_ror:1
        int s = g * 4 + r;
        if (s < UU) { mval = fmaxf(mval, part); sval += part; }
    }
    mval = fmaxf(mval, __shfl_xor(mval, 16, 64));
    sval += __shfl_xor(sval, 16, 64);
    mval = fmaxf(mval, __shfl_xor(mval, 32, 64));
    sval += __shfl_xor(sval, 32, 64);
    if (lane == 0) M[bh * LL + q] = mval - sval * (1.0f / LL);
}

// ---------------- Kernel 1: computeM + tilesum (full-grid TLP) ----------------
__global__ __launch_bounds__(256, 2) void k_computeM_tilesum(
        const float* __restrict__ Q, const float* __restrict__ K,
        const int* __restrict__ idx, const float* __restrict__ V,
        float* __restrict__ M, float* __restrict__ tsum) {
    if (blockIdx.x >= NB_CMU) {
        // ---- tilesum branch ----
        int blk = blockIdx.x - NB_CMU; // ((b*HH+h)*NTILES + tile)
        int tile = blk % NTILES;
        int bh = blk / NTILES;
        int h = bh % HH, b = bh / HH;
        int d = threadIdx.x & 63, g = threadIdx.x >> 6; // g in 0..3
        const int CH = TILE / 4;                        // 32
        int l0 = tile * TILE + g * CH;
        float acc = 0.f;
        for (int i = 0; i < CH; ++i) acc += V[qkv_idx(b, l0 + i, h, d)];
        __shared__ float red[4][DD];
        red[g][d] = acc;
        __syncthreads();
        if (g == 0)
            tsum[blk * DD + d] =
                red[0][d] + red[1][d] + red[2][d] + red[3][d];
        return;
    }
    computeM_unit(blockIdx.x * 4 + (threadIdx.x >> 6), threadIdx.x & 63,
                  Q, K, idx, M);
}

// ---------------- Kernel 2: top-45 via 4-pass 8-bit radix select --------------
// ROUND-15 LESSON: single 12-bit-MSB pass is refuted -- M values concentrate
// (sign+exp+3 mantissa bits -> ~16 effective bins), boundary bin >> 64 keys,
// serial fallback fired (113us, VALUBusy 0.1%). The 4-pass conditional-prefix
// radix (proven in rounds 8-10 at ~185us totals) never degenerates: each pass
// refines WITHIN the surviving prefix. Single-wave 256-bin suffix scan kept.
__global__ __launch_bounds__(1024) void k_topk(
        const float* __restrict__ M, int* __restrict__ Mtop,
        unsigned* __restrict__ selmap) {
    int bh = blockIdx.x;
    int t = threadIdx.x;
    __shared__ unsigned keys[LL];      // 16 KB
    __shared__ unsigned hist[256];
    __shared__ unsigned scanbuf[256];
    __shared__ unsigned sPrefix, sMask, sK, sBin;
    __shared__ int outCount, eqCount;
    __shared__ int eqIdx[64];

    for (int i = t; i < LL; i += 1024) {
        unsigned u = __float_as_uint(M[bh * LL + i]);
        keys[i] = (u & 0x80000000u) ? ~u : (u | 0x80000000u);
    }
    if (selmap != nullptr && t < 128) selmap[bh * 128 + t] = 0u;
    if (t == 0) { sPrefix = 0u; sMask = 0u; sK = UU; outCount = 0; eqCount = 0; }
    __syncthreads();

    for (int pass = 0; pass < 4; ++pass) {
        int shift = 24 - pass * 8;
        if (t < 256) hist[t] = 0u;
        __syncthreads();
        unsigned prefix = sPrefix, mask = sMask;
        for (int i = t; i < LL; i += 1024) {
            unsigned k = keys[i];
            if ((k & mask) == prefix)
                atomicAdd(&hist[(k >> shift) & 0xFFu], 1u);
        }
        __syncthreads();
        // single-wave 256-bin suffix scan: lane l owns bins 4l..4l+3
        if (t < 64) {
            int l = t;
            unsigned h0 = hist[4 * l + 0], h1 = hist[4 * l + 1];
            unsigned h2 = hist[4 * l + 2], h3 = hist[4 * l + 3];
            unsigned s3 = h3, s2 = h2 + s3, s1 = h1 + s2, s0 = h0 + s1;
            unsigned tot = s0, inc = tot;
#pragma unroll
            for (int off = 1; off < 64; off <<= 1) {
                unsigned x = __shfl_down(inc, off, 64);
                if (l + off < 64) inc += x;
            }
            unsigned above = inc - tot; // sum over lanes > l
            scanbuf[4 * l + 0] = s0 + above;
            scanbuf[4 * l + 1] = s1 + above;
            scanbuf[4 * l + 2] = s2 + above;
            scanbuf[4 * l + 3] = s3 + above;
        }
        __syncthreads();
        if (t < 256) {
            unsigned k = sK;
            unsigned geq = scanbuf[t];
            unsigned gt = (t < 255) ? scanbuf[t + 1] : 0u;
            if (gt < k && geq >= k) sBin = (unsigned)t;
        }
        __syncthreads();
        if (t == 0) {
            unsigned b = sBin;
            unsigned gt = (b < 255u) ? scanbuf[b + 1] : 0u;
            sK -= gt;
            sPrefix |= (b << shift);
            sMask |= (0xFFu << shift);
        }
        __syncthreads();
    }
    unsigned T = sPrefix;
    int kEq = (int)sK;

    for (int i = t; i < LL; i += 1024) {
        unsigned k = keys[i];
        if (k > T) {
            int slot = atomicAdd(&outCount, 1);
            Mtop[bh * UU + slot] = i;
        } else if (k == T) {
            int e = atomicAdd(&eqCount, 1);
            if (e < 64) eqIdx[e] = i;
        }
    }
    __syncthreads();

    if (t == 0) {
        int base = outCount; // == UU - kEq
        int ec = eqCount;
        if (ec <= 64) {
            for (int s = 0; s < UU; ++s) { // s < kEq, bounded loop for compiler
                if (s >= kEq) break;
                int bi = -1, bv = LL + 2;
                for (int j = 0; j < ec; ++j) {
                    int v = eqIdx[j];
                    if (v < bv) { bv = v; bi = j; }
                }
                Mtop[bh * UU + base + s] = bv;
                eqIdx[bi] = LL + 2;
            }
        } else {
            // paranoid fallback (massive duplicate values): serial lowest-index
            int got = 0;
            for (int i = 0; i < LL && got < kEq; ++i)
                if (keys[i] == T) { Mtop[bh * UU + base + got] = i; ++got; }
        }
    }
    __syncthreads();
    if (selmap != nullptr && t < UU) {
        int qi = Mtop[bh * UU + t];
        atomicOr(&selmap[bh * 128 + (qi >> 5)], 1u << (qi & 31));
    }
}

// ---------------- unit: split-K flash attention partial (256 threads) --------
__device__ void attn_unit(int bh, int c, int t,
        const float* __restrict__ Q, const float* __restrict__ K,
        const float* __restrict__ V, const int* __restrict__ Mtop,
        float* __restrict__ mPart, float* __restrict__ lPart,
        float* __restrict__ Op, SmemAttn* s) {
    int h = bh % HH, b = bh / HH;
    int k0 = c * CK;

    const size_t rowStride = (size_t)HH * DD; // 512 floats
    const float* Qbh = Q + (size_t)(b * LL * HH + h) * DD;
    const float* Kbh = K + (size_t)(b * LL * HH + h) * DD;
    const float* Vbh = V + (size_t)(b * LL * HH + h) * DD;

    for (int p = t; p < 48 * DD; p += 256) {
        int u = p >> 6, d = p & 63;
        float v = 0.f;
        if (u < UU) {
            int qi = Mtop[bh * UU + u];
            v = Qbh[(size_t)qi * rowStride + d] * 0.125f;
        }
        s->Qs[u * KSTR + d] = v;
    }
    for (int p = t; p < CK * 16; p += 256) {
        int row = p >> 4, i = p & 15;
        *(float4*)&s->Ks[row * KSTR + i * 4] =
            *(const float4*)&Kbh[(size_t)(k0 + row) * rowStride + i * 4];
    }
    __syncthreads();

    // --- scores GEMM: thread tile 3u x 4k ---
    int kq = t & 15, uq = t >> 4;
    int u0 = uq * 3;
    float acc[3][4];
#pragma unroll
    for (int i = 0; i < 3; ++i)
#pragma unroll
        for (int j = 0; j < 4; ++j) acc[i][j] = 0.f;

#pragma unroll 4
    for (int dd = 0; dd < 16; ++dd) {
        float4 qf[3];
#pragma unroll
        for (int i = 0; i < 3; ++i)
            qf[i] = *(const float4*)&s->Qs[(u0 + i) * KSTR + dd * 4];
        float4 kf[4];
#pragma unroll
        for (int j = 0; j < 4; ++j)
            kf[j] = *(const float4*)&s->Ks[(kq + 16 * j) * KSTR + dd * 4];
#pragma unroll
        for (int i = 0; i < 3; ++i)
#pragma unroll
            for (int j = 0; j < 4; ++j) {
                acc[i][j] = fmaf(qf[i].x, kf[j].x, acc[i][j]);
                acc[i][j] = fmaf(qf[i].y, kf[j].y, acc[i][j]);
                acc[i][j] = fmaf(qf[i].z, kf[j].z, acc[i][j]);
                acc[i][j] = fmaf(qf[i].w, kf[j].w, acc[i][j]);
            }
    }
#pragma unroll
    for (int i = 0; i < 3; ++i) {
        int u = u0 + i;
        if (u < UU)
#pragma unroll
            for (int j = 0; j < 4; ++j)
                s->Ss[u * SSTR + kq + 16 * j] = acc[i][j];
    }
    __syncthreads();

    // stage V chunk into the K buffer (no one reads Ks until next barrier)
    for (int p = t; p < CK * 16; p += 256) {
        int row = p >> 4, i = p & 15;
        *(float4*)&s->Ks[row * KSTR + i * 4] =
            *(const float4*)&Vbh[(size_t)(k0 + row) * rowStride + i * 4];
    }

    // --- chunk-local softmax: 4 threads per u ---
    if (t < UU * 4) {
        int u = t >> 2, qq = t & 3;
        float mloc = -INFINITY;
        for (int j = 0; j < CK / 4; ++j)
            mloc = fmaxf(mloc, s->Ss[u * SSTR + qq + 4 * j]);
        mloc = fmaxf(mloc, __shfl_xor(mloc, 1, 64));
        mloc = fmaxf(mloc, __shfl_xor(mloc, 2, 64));
        float lloc = 0.f;
        for (int j = 0; j < CK / 4; ++j) {
            int kk = qq + 4 * j;
            float e = __expf(s->Ss[u * SSTR + kk] - mloc);
            s->Ss[u * SSTR + kk] = e;
            lloc += e;
        }
        lloc += __shfl_xor(lloc, 1, 64);
        lloc += __shfl_xor(lloc, 2, 64);
        if (qq == 0) {
            mPart[(bh * NC + c) * UU + u] = mloc;
            lPart[(bh * NC + c) * UU + u] = lloc;
        }
    }
    __syncthreads();

    // --- PV GEMM: thread tile 3u x 4d ---
    int dq = t & 15;
    int d0 = dq * 4;
    if (u0 < UU) { // uq==15 idle
        float4 o[3];
#pragma unroll
        for (int i = 0; i < 3; ++i) o[i] = make_float4(0.f, 0.f, 0.f, 0.f);
#pragma unroll 4
        for (int kc = 0; kc < CK / 4; ++kc) {
            float4 vk[4];
#pragma unroll
            for (int jj = 0; jj < 4; ++jj)
                vk[jj] = *(const float4*)&s->Ks[(4 * kc + jj) * KSTR + d0];
#pragma unroll
            for (int i = 0; i < 3; ++i) {
                float4 pf = *(const float4*)&s->Ss[(u0 + i) * SSTR + 4 * kc];
                o[i].x = fmaf(pf.x, vk[0].x, o[i].x);
                o[i].y = fmaf(pf.x, vk[0].y, o[i].y);
                o[i].z = fmaf(pf.x, vk[0].z, o[i].z);
                o[i].w = fmaf(pf.x, vk[0].w, o[i].w);
                o[i].x = fmaf(pf.y, vk[1].x, o[i].x);
                o[i].y = fmaf(pf.y, vk[1].y, o[i].y);
                o[i].z = fmaf(pf.y, vk[1].z, o[i].z);
                o[i].w = fmaf(pf.y, vk[1].w, o[i].w);
                o[i].x = fmaf(pf.z, vk[2].x, o[i].x);
                o[i].y = fmaf(pf.z, vk[2].y, o[i].y);
                o[i].z = fmaf(pf.z, vk[2].z, o[i].z);
                o[i].w = fmaf(pf.z, vk[2].w, o[i].w);
                o[i].x = fmaf(pf.w, vk[3].x, o[i].x);
                o[i].y = fmaf(pf.w, vk[3].y, o[i].y);
                o[i].z = fmaf(pf.w, vk[3].z, o[i].z);
                o[i].w = fmaf(pf.w, vk[3].w, o[i].w);
            }
        }
#pragma unroll
        for (int i = 0; i < 3; ++i) {
            int u = u0 + i;
            *(float4*)&Op[((size_t)(bh * NC + c) * UU + u) * DD + d0] = o[i];
        }
    }
}

// ---------------- unit: cumsum tile ------------------------------------------
__device__ void cumsum_unit(int blk, int t, const float* __restrict__ V,
        const float* __restrict__ tsum, const unsigned* __restrict__ selmap,
        float* __restrict__ out, SmemSum* s) {
    int tile = blk % NTILES;
    int bh = blk / NTILES;
    int h = bh % HH, b = bh / HH;
    int d = t & 63, g = t >> 6;
    const int CH = TILE / 4;
    int l0 = tile * TILE + g * CH;

    float acc = 0.f;
    for (int i = 0; i < CH; ++i) acc += V[qkv_idx(b, l0 + i, h, d)];
    s->red[g][d] = acc;
    float p = 0.f;
    for (int tt = g; tt < tile; tt += 4)
        p += tsum[(bh * NTILES + tt) * DD + d];
    s->pre2[g][d] = p;
    __syncthreads();

    float off = s->pre2[0][d] + s->pre2[1][d] + s->pre2[2][d] + s->pre2[3][d];
    for (int gg = 0; gg < g; ++gg) off += s->red[gg][d];

    unsigned selw = (selmap != nullptr) ? selmap[bh * 128 + (l0 >> 5)] : 0u;

    float run = off;
    for (int i = 0; i < CH; ++i) {
        run += V[qkv_idx(b, l0 + i, h, d)];
        if (!((selw >> i) & 1u))
            out[qkv_idx(b, l0 + i, h, d)] = run;
    }
}

// ---------------- Kernel 3: attn partials ∥ cumsum (independent given topk) ---
// cumsum depends only on selmap+tsum, not on attn -- appending its 512 blocks
// to attn's 1024 lets the two overlap (same-stream kernels serialize, so this
// is the only way). Both write disjoint out rows vs k_combine.
__global__ __launch_bounds__(256) void k_attn_cumsum(
        const float* __restrict__ Q, const float* __restrict__ K,
        const float* __restrict__ V, const int* __restrict__ Mtop,
        const float* __restrict__ tsum, const unsigned* __restrict__ selmap,
        float* __restrict__ mPart, float* __restrict__ lPart,
        float* __restrict__ Op, float* __restrict__ out) {
    __shared__ __align__(16) char smem[sizeof(SmemAttn)];
    if (blockIdx.x < NB_AT)
        attn_unit(blockIdx.x / NC, blockIdx.x % NC, threadIdx.x, Q, K, V,
                  Mtop, mPart, lPart, Op, (SmemAttn*)smem);
    else
        cumsum_unit(blockIdx.x - NB_AT, threadIdx.x, V, tsum, selmap, out,
                    (SmemSum*)smem);
}

// ---------------- Kernel 4: flash combine across chunks, scatter --------------
__global__ void k_combine(
        const int* __restrict__ Mtop, const float* __restrict__ mPart,
        const float* __restrict__ lPart, const float* __restrict__ Op,
        float* __restrict__ out) {
    int t = threadIdx.x;
    int u4 = blockIdx.x * 4 + (t >> 6); // 0..719
    int u = u4 % UU;
    int bh = u4 / UU;
    int h = bh % HH, b = bh / HH;
    int d = t & 63;
    float gm = -INFINITY;
    for (int c = 0; c < NC; ++c)
        gm = fmaxf(gm, mPart[(bh * NC + c) * UU + u]);
    float denom = 0.f, acc = 0.f;
    for (int c = 0; c < NC; ++c) {
        int pi = (bh * NC + c) * UU + u;
        float w = __expf(mPart[pi] - gm);
        denom = fmaf(lPart[pi], w, denom);
        acc = fmaf(w, Op[(size_t)pi * DD + d], acc);
    }
    int qi = Mtop[bh * UU + u];
    out[qkv_idx(b, qi, h, d)] = acc / denom;
}

// ---------------- fallbacks (compact-ws path) ---------------------------------
__global__ __launch_bounds__(256) void k_cumsum_fb(
        const float* __restrict__ V, const float* __restrict__ tsum,
        float* __restrict__ out) {
    __shared__ SmemSum s;
    cumsum_unit(blockIdx.x, threadIdx.x, V, tsum, (const unsigned*)nullptr,
                out, &s);
}

__global__ __launch_bounds__(256) void k_attn_mono(
        const float* __restrict__ Q, const float* __restrict__ K,
        const float* __restrict__ V, const int* __restrict__ Mtop,
        float* __restrict__ out) {
    int blk = blockIdx.x; // bh*UU + u
    int u = blk % UU;
    int bh = blk / UU;
    int h = bh % HH, b = bh / HH;
    int qi = Mtop[bh * UU + u];
    int t = threadIdx.x;

    __shared__ float scores[LL];
    __shared__ float red[256];

    const float4* qp = (const float4*)(Q + qkv_idx(b, qi, h, 0));
    float4 qreg[16];
#pragma unroll
    for (int i = 0; i < 16; ++i) {
        float4 v = qp[i];
        v.x *= 0.125f; v.y *= 0.125f; v.z *= 0.125f; v.w *= 0.125f;
        qreg[i] = v;
    }

    float lmax = -INFINITY;
    for (int k = t; k < LL; k += 256) {
        const float4* kr = (const float4*)(K + qkv_idx(b, k, h, 0));
        float dot = 0.f;
#pragma unroll
        for (int i = 0; i < 16; ++i) {
            float4 kk = kr[i];
            dot = fmaf(qreg[i].x, kk.x, dot);
            dot = fmaf(qreg[i].y, kk.y, dot);
            dot = fmaf(qreg[i].z, kk.z, dot);
            dot = fmaf(qreg[i].w, kk.w, dot);
        }
        scores[k] = dot;
        lmax = fmaxf(lmax, dot);
    }
    red[t] = lmax;
    __syncthreads();
    for (int off = 128; off >= 1; off >>= 1) {
        if (t < off) red[t] = fmaxf(red[t], red[t + off]);
        __syncthreads();
    }
    float smax = red[0];
    __syncthreads();

    float lsum = 0.f;
    for (int k = t; k < LL; k += 256) {
        float e = __expf(scores[k] - smax);
        scores[k] = e;
        lsum += e;
    }
    red[t] = lsum;
    __syncthreads();
    for (int off = 128; off >= 1; off >>= 1) {
        if (t < off) red[t] += red[t + off];
        __syncthreads();
    }
    float denom = red[0];
    __syncthreads();

    int d = t & 63, g = t >> 6;
    const float4* sc4 = (const float4*)scores;
    float acc = 0.f;
    for (int kb = g; kb < LL / 4; kb += 4) {
        float4 s4 = sc4[kb];
        int kk0 = kb * 4;
        acc = fmaf(s4.x, V[qkv_idx(b, kk0 + 0, h, d)], acc);
        acc = fmaf(s4.y, V[qkv_idx(b, kk0 + 1, h, d)], acc);
        acc = fmaf(s4.z, V[qkv_idx(b, kk0 + 2, h, d)], acc);
        acc = fmaf(s4.w, V[qkv_idx(b, kk0 + 3, h, d)], acc);
    }
    red[t] = acc;
    __syncthreads();
    if (g == 0) {
        float s = red[d] + red[64 + d] + red[128 + d] + red[192 + d];
        out[qkv_idx(b, qi, h, d)] = s / denom;
    }
}

extern "C" void kernel_launch(void* const* d_in, const int* in_sizes, int n_in,
                              void* d_out, int out_size, void* d_ws, size_t ws_size,
                              hipStream_t stream) {
    const float* Q = (const float*)d_in[0];
    const float* K = (const float*)d_in[1];
    const float* V = (const float*)d_in[2];
    const int* idx = (const int*)d_in[3];
    float* out = (float*)d_out;

    float* ws = (float*)d_ws;

    // workspace layout (floats)
    const size_t M_off = 0;                           // 65536
    const size_t tsum_off = 65536;                    // 32768
    const size_t mP_off = 98304;                      // 16*64*45 = 46080
    const size_t lP_off = 144384;                     // 46080
    const size_t top_off = 190464;                    // 720 ints (reserve 1024)
    const size_t sel_off = 191488;                    // 16*128 uints (2048)
    const size_t Op_off = 193536;                     // 16*64*45*64 = 2949120
    const size_t need = (Op_off + (size_t)BB * HH * NC * UU * DD) * 4;

    float* M = ws + M_off;
    float* tsum = ws + tsum_off;

    if (ws_size >= need) {
        float* mPart = ws + mP_off;
        float* lPart = ws + lP_off;
        int* Mtop = (int*)(ws + top_off);
        unsigned* selmap = (unsigned*)(ws + sel_off);
        float* Op = ws + Op_off;

        k_computeM_tilesum<<<NB_CMU + NB_TS, 256, 0, stream>>>(Q, K, idx, V,
                                                               M, tsum);
        k_topk<<<BB * HH, 1024, 0, stream>>>(M, Mtop, selmap);
        k_attn_cumsum<<<NB_AT + NB_CU, 256, 0, stream>>>(
            Q, K, V, Mtop, tsum, selmap, mPart, lPart, Op, out);
        k_combine<<<NB_CO, 256, 0, stream>>>(Mtop, mPart, lPart, Op, out);
    } else {
        // compact fallback layout
        int* Mtop = (int*)(ws + 65536);
        float* tsum2 = ws + 65536 + 1024;
        k_computeM_tilesum<<<NB_CMU + NB_TS, 256, 0, stream>>>(Q, K, idx, V,
                                                               M, tsum2);
        k_topk<<<BB * HH, 1024, 0, stream>>>(M, Mtop, (unsigned*)nullptr);
        k_cumsum_fb<<<BB * HH * NTILES, 256, 0, stream>>>(V, tsum2, out);
        k_attn_mono<<<BB * HH * UU, 256, 0, stream>>>(Q, K, V, Mtop, out);
    }
}